// Round 7
// baseline (844.768 us; speedup 1.0000x reference)
//
#include <hip/hip_runtime.h>

#define N_NODES 50000
#define N_EDGES 800000
#define E_TOT   (N_EDGES + N_NODES)   // with self loops
#define HID     128

typedef unsigned short u16;
typedef unsigned int   u32;
typedef __bf16 bf16x8 __attribute__((ext_vector_type(8)));
typedef float  f32x4  __attribute__((ext_vector_type(4)));

__device__ __forceinline__ float b2f(u16 u) {
  union { u32 i; float f; } c; c.i = ((u32)u) << 16; return c.f;
}
__device__ __forceinline__ u16 f2b(float f) {
  union { float f; u32 i; } c; c.f = f;
  u32 u = c.i;
  return (u16)((u + 0x7fffu + ((u >> 16) & 1u)) >> 16);  // RNE
}

// ---------------- runtime dtype detection ----------------

__global__ void k_detect(const void* x, const void* ei, int* flags) {
  int lane = threadIdx.x;              // 64 threads
  const u16* xw = (const u16*)x;
  int wildF = 0;
  #pragma unroll
  for (int i = 0; i < 4; ++i) {
    u16 w = xw[lane + 64 * i];
    int e = (w >> 7) & 0xff;
    if (e >= 0x89) wildF = 1;          // |bf16| >= 1024: impossible for N(0,1) bf16
  }
  unsigned long long bF = __ballot(wildF);
  const int* e32 = (const int*)ei;
  int nzOdd = 0;
  #pragma unroll
  for (int i = 0; i < 2; ++i)
    if (e32[2 * (lane + 64 * i) + 1] != 0) nzOdd = 1;
  unsigned long long bI = __ballot(nzOdd);
  if (lane == 0) {
    flags[0] = (bF != 0ull) ? 1 : 0;
    flags[1] = (bI != 0ull) ? 0 : 1;   // odd words all zero -> int64
  }
}

// ---------------- param conversion: weights -> bf16 hi/lo planes, vectors -> f32 ----------------

__global__ __launch_bounds__(256) void k_convert(
    const void* Wenc, const void* Wg, const void* Wd, const void* Wd1,
    const void* benc, const void* bg, const void* atts, const void* attd,
    const void* bd, const void* bd1, const void* Wh, const void* bh,
    const void* Wt, const void* bt,
    u16* WencH, u16* WencL, u16* WgH, u16* WgL, u16* WdH, u16* WdL,
    u16* Wd1H, u16* Wd1L, float* vecf, const int* flags)
{
  int isF32 = flags[0];
  int t = blockIdx.x * 256 + threadIdx.x;
  auto ld = [&](const void* p, int i) -> float {
    return isF32 ? ((const float*)p)[i] : b2f(((const u16*)p)[i]);
  };
  auto sp = [&](u16* H, u16* L, int i, float v) {
    u16 hh = f2b(v); H[i] = hh; L[i] = f2b(v - b2f(hh));
  };
  if      (t < 24576)  { sp(WencH, WencL, t, ld(Wenc, t)); }
  else if (t < 73728)  { int i = t - 24576;  sp(WgH,  WgL,  i, ld(Wg, i)); }
  else if (t < 106496) { int i = t - 73728;  sp(WdH,  WdL,  i, ld(Wd, i)); }
  else if (t < 122880) { int i = t - 106496; sp(Wd1H, Wd1L, i, ld(Wd1, i)); }
  else if (t < 123008) { int i = t - 122880; vecf[i]        = ld(benc, i); }
  else if (t < 123392) { int i = t - 123008; vecf[128 + i]  = ld(bg, i); }
  else if (t < 123776) { int i = t - 123392; vecf[512 + i]  = ld(atts, i); }
  else if (t < 124160) { int i = t - 123776; vecf[896 + i]  = ld(attd, i); }
  else if (t < 124288) { int i = t - 124160; vecf[1280 + i] = ld(bd, i); }
  else if (t < 124416) { int i = t - 124288; vecf[1408 + i] = ld(bd1, i); }
  else if (t < 124544) { int i = t - 124416; vecf[1536 + i] = ld(Wh, i); }
  else if (t == 124544) { vecf[1664] = ld(bh, 0); }
  else if (t < 124673) { int i = t - 124545; vecf[1665 + i] = ld(Wt, i); }
  else if (t == 124673) { vecf[1793] = ld(bt, 0); }
}

// ---------------- waS/waD = Wg^T @ att vectors (3 layers) ----------------

__global__ void k_wa(const u16* __restrict__ WgH, const u16* __restrict__ WgL,
                     const float* __restrict__ vecf, float* __restrict__ waS, float* __restrict__ waD) {
  int t = blockIdx.x * 256 + threadIdx.x;   // 768 items: (l, sel, k)
  if (t >= 768) return;
  int l = t / 256, sel = (t / 128) & 1, k = t & 127;
  const float* av = vecf + (sel ? 896 : 512) + l * HID;
  const u16* H = WgH + (size_t)l * HID * HID;
  const u16* L = WgL + (size_t)l * HID * HID;
  float s = 0.0f;
  for (int c = 0; c < HID; ++c)
    s += (b2f(H[(size_t)c * HID + k]) + b2f(L[(size_t)c * HID + k])) * av[c];
  (sel ? waD : waS)[l * HID + k] = s;
}

// ---------------- CSR build ----------------

__device__ __forceinline__ int ld_ei(const int* ei, size_t idx, int i64) {
  int v = i64 ? (int)((const long long*)ei)[idx] : ei[idx];
  return ((unsigned)v < (unsigned)N_NODES) ? v : 0;  // defensive clamp
}

__global__ void k_deg(const int* __restrict__ ei, int* __restrict__ deg, const int* flags) {
  int i64 = flags[1];
  int k = blockIdx.x * 256 + threadIdx.x;
  if (k >= E_TOT) return;
  int d = (k < N_EDGES) ? ld_ei(ei, (size_t)N_EDGES + k, i64) : (k - N_EDGES);
  atomicAdd(&deg[d], 1);
}

__device__ __forceinline__ int block_scan_excl(int v, int lane, int w, int* wsum, int& total) {
  int x = v;
  #pragma unroll
  for (int d = 1; d < 64; d <<= 1) {
    int y = __shfl_up(x, d);
    if (lane >= d) x += y;
  }
  if (lane == 63) wsum[w] = x;
  __syncthreads();
  int wOff = 0;
  #pragma unroll
  for (int i = 0; i < 4; ++i) wOff += (i < w) ? wsum[i] : 0;
  total = wsum[0] + wsum[1] + wsum[2] + wsum[3];
  return wOff + x - v;  // exclusive
}

__global__ void k_scan_block(const int* __restrict__ in, int* __restrict__ outExcl,
                             int* __restrict__ blkSum, int n, int* __restrict__ totalOut) {
  __shared__ int wsum[4];
  int t = threadIdx.x, lane = t & 63, w = t >> 6;
  int gid = blockIdx.x * 256 + t;
  int v = (gid < n) ? in[gid] : 0;
  int total;
  int excl = block_scan_excl(v, lane, w, wsum, total);
  if (gid < n) outExcl[gid] = excl;
  if (t == 0) {
    if (blkSum)   blkSum[blockIdx.x] = total;
    if (totalOut) totalOut[0] = total;
  }
}

__global__ void k_scan_add(int* __restrict__ rowp, const int* __restrict__ blkOff,
                           int* __restrict__ cursor, int n) {
  int gid = blockIdx.x * 256 + threadIdx.x;
  if (gid < n) {
    int r = rowp[gid] + blkOff[blockIdx.x];
    rowp[gid] = r;
    cursor[gid] = r;
  }
}

__global__ void k_scatter(const int* __restrict__ ei, int* __restrict__ cursor,
                          int* __restrict__ colsrc, const int* flags) {
  int i64 = flags[1];
  int k = blockIdx.x * 256 + threadIdx.x;
  if (k >= E_TOT) return;
  int s, d;
  if (k < N_EDGES) { s = ld_ei(ei, k, i64); d = ld_ei(ei, (size_t)N_EDGES + k, i64); }
  else             { s = d = k - N_EDGES; }
  int pos = atomicAdd(&cursor[d], 1);
  colsrc[pos] = s;
}

// ---------------- MFMA GEMM, split-bf16 3-term ----------------
// out[N,128] = concat(A1,A2)[N,K] @ W[128,K]^T (+bias)(+relu).
// aMode 1: A raw inputs (f32 split on the fly / bf16). aMode 2: A bf16 hi/lo planes.

__device__ __forceinline__ void loadSplit8(const float* p, bf16x8& hi, bf16x8& lo) {
  union { u16 a[8]; bf16x8 v; } H, L;
  #pragma unroll
  for (int i = 0; i < 8; ++i) {
    float v = p[i];
    u16 hh = f2b(v);
    H.a[i] = hh;
    L.a[i] = f2b(v - b2f(hh));
  }
  hi = H.v; lo = L.v;
}

__global__ __launch_bounds__(256) void k_gemm(
    const void* A1a, const void* A1b, int s1, int K1,
    const void* A2a, const void* A2b, int s2,
    const u16* __restrict__ WH, const u16* __restrict__ WL,
    const float* __restrict__ biasF,
    float* __restrict__ outF_, u16* __restrict__ outH, u16* __restrict__ outL,
    int N, int K, int relu, int aMode, const int* flags)
{
  int isF32 = flags[0];
  int wid  = blockIdx.x * 4 + (threadIdx.x >> 6);
  int lane = threadIdx.x & 63;
  int q = lane >> 4, c = lane & 15;
  int nb = wid * 32;
  if (nb >= N) return;
  f32x4 acc[2][8] = {};
  int r0 = nb + c;      if (r0 > N - 1) r0 = N - 1;
  int r1 = nb + 16 + c; if (r1 > N - 1) r1 = N - 1;

  for (int kb = 0; kb < K; kb += 32) {
    int kf = kb + q * 8;                   // lane's 8 contiguous k
    bf16x8 a0h, a1h, a0l, a1l;
    if (aMode == 1) {
      const void* Ap; int stride, ks;
      if (kf < K1) { Ap = A1a; stride = s1; ks = kf; }
      else         { Ap = A2a; stride = s2; ks = kf - K1; }
      if (isF32) {
        loadSplit8((const float*)Ap + (size_t)r0 * stride + ks, a0h, a0l);
        loadSplit8((const float*)Ap + (size_t)r1 * stride + ks, a1h, a1l);
      } else {
        union { u16 u[8]; bf16x8 v; } Z = {};
        a0h = *(const bf16x8*)((const u16*)Ap + (size_t)r0 * stride + ks);
        a1h = *(const bf16x8*)((const u16*)Ap + (size_t)r1 * stride + ks);
        a0l = Z.v; a1l = Z.v;
      }
    } else {
      const u16 *PH, *PL; int stride, ks;
      if (kf < K1) { PH = (const u16*)A1a; PL = (const u16*)A1b; stride = s1; ks = kf; }
      else         { PH = (const u16*)A2a; PL = (const u16*)A2b; stride = s2; ks = kf - K1; }
      a0h = *(const bf16x8*)(PH + (size_t)r0 * stride + ks);
      a0l = *(const bf16x8*)(PL + (size_t)r0 * stride + ks);
      a1h = *(const bf16x8*)(PH + (size_t)r1 * stride + ks);
      a1l = *(const bf16x8*)(PL + (size_t)r1 * stride + ks);
    }
    const u16* wph = WH + (size_t)c * K + kb + q * 8;
    const u16* wpl = WL + (size_t)c * K + kb + q * 8;
    #pragma unroll
    for (int ct = 0; ct < 8; ++ct) {
      bf16x8 bh_ = *(const bf16x8*)(wph + (size_t)(ct * 16) * K);
      bf16x8 bl_ = *(const bf16x8*)(wpl + (size_t)(ct * 16) * K);
      acc[0][ct] = __builtin_amdgcn_mfma_f32_16x16x32_bf16(a0h, bh_, acc[0][ct], 0, 0, 0);
      acc[1][ct] = __builtin_amdgcn_mfma_f32_16x16x32_bf16(a1h, bh_, acc[1][ct], 0, 0, 0);
      acc[0][ct] = __builtin_amdgcn_mfma_f32_16x16x32_bf16(a0h, bl_, acc[0][ct], 0, 0, 0);
      acc[1][ct] = __builtin_amdgcn_mfma_f32_16x16x32_bf16(a1h, bl_, acc[1][ct], 0, 0, 0);
      acc[0][ct] = __builtin_amdgcn_mfma_f32_16x16x32_bf16(a0l, bh_, acc[0][ct], 0, 0, 0);
      acc[1][ct] = __builtin_amdgcn_mfma_f32_16x16x32_bf16(a1l, bh_, acc[1][ct], 0, 0, 0);
    }
  }

  // epilogue: bias/relu + stores
  #pragma unroll
  for (int ct = 0; ct < 8; ++ct) {
    int col = ct * 16 + c;
    float bv = biasF ? biasF[col] : 0.0f;
    #pragma unroll
    for (int g = 0; g < 2; ++g) {
      #pragma unroll
      for (int r = 0; r < 4; ++r) {
        float vv = acc[g][ct][r] + bv;
        if (relu) vv = fmaxf(vv, 0.0f);
        int node = nb + g * 16 + q * 4 + r;
        if (node < N) {
          size_t o = (size_t)node * HID + col;
          if (outF_) outF_[o] = vv;
          if (outH) {
            u16 hh = f2b(vv);
            outH[o] = hh;
            outL[o] = f2b(vv - b2f(hh));
          }
        }
      }
    }
  }
}

// ---------------- layer-0 attention dots from z planes: ssrc = z·waS0, sdst = z·waD0 ----------------

__global__ __launch_bounds__(256) void k_sdots(const u16* __restrict__ zH, const u16* __restrict__ zL,
    const float* __restrict__ waS0, const float* __restrict__ waD0,
    float* __restrict__ ssrc, float* __restrict__ sdst)
{
  int node = blockIdx.x * 4 + (threadIdx.x >> 6);
  int lane = threadIdx.x & 63;
  size_t o = (size_t)node * HID + lane * 2;
  u32 ph = *(const u32*)(zH + o);
  u32 pl = *(const u32*)(zL + o);
  float v0 = b2f((u16)ph) + b2f((u16)pl);
  float v1 = b2f((u16)(ph >> 16)) + b2f((u16)(pl >> 16));
  float vs = v0 * waS0[lane * 2] + v1 * waS0[lane * 2 + 1];
  float vd = v0 * waD0[lane * 2] + v1 * waD0[lane * 2 + 1];
  #pragma unroll
  for (int d = 1; d < 64; d <<= 1) { vs += __shfl_xor(vs, d); vd += __shfl_xor(vd, d); }
  if (lane == 0) { ssrc[node] = vs; sdst[node] = vd; }
}

// ---------------- per-dst softmax over incoming edges ----------------

__global__ __launch_bounds__(256) void k_softmax(const int* __restrict__ rowp,
    const int* __restrict__ colsrc, const float* __restrict__ ssrc,
    const float* __restrict__ sdst, float* __restrict__ alpha)
{
  int node = blockIdx.x * 4 + (threadIdx.x >> 6);
  int lane = threadIdx.x & 63;
  int start = rowp[node], end = rowp[node + 1];
  float sdv = sdst[node];
  float mx = -1e30f;
  for (int j = start + lane; j < end; j += 64) {
    float e = ssrc[colsrc[j]] + sdv;
    e = (e >= 0.0f) ? e : 0.2f * e;      // leaky_relu 0.2
    alpha[j] = e;
    mx = fmaxf(mx, e);
  }
  #pragma unroll
  for (int d = 1; d < 64; d <<= 1) mx = fmaxf(mx, __shfl_xor(mx, d));
  float sum = 0.0f;
  for (int j = start + lane; j < end; j += 64) {
    float ex = __expf(alpha[j] - mx);
    alpha[j] = ex;
    sum += ex;
  }
  #pragma unroll
  for (int d = 1; d < 64; d <<= 1) sum += __shfl_xor(sum, d);
  float inv = 1.0f / sum;                // self loop -> sum > 0
  for (int j = start + lane; j < end; j += 64) alpha[j] *= inv;
}

// ---------------- weighted gather: deep-MLP, writes planes + next-layer att dots ----------------

__global__ __launch_bounds__(256) void k_gather(const int* __restrict__ rowp,
    const int* __restrict__ colsrc, const float* __restrict__ alpha,
    const float* __restrict__ xw, const float* __restrict__ biasF,
    u16* __restrict__ outH, u16* __restrict__ outL,
    float* __restrict__ out2,
    const float* __restrict__ waSn, const float* __restrict__ waDn,
    float* __restrict__ ssrc, float* __restrict__ sdst, int relu)
{
  int node = blockIdx.x * 4 + (threadIdx.x >> 6);
  int lane = threadIdx.x & 63;
  int half = lane >> 5, hl = lane & 31;
  int start = rowp[node], end = rowp[node + 1];
  float a0 = 0, a1 = 0, a2 = 0, a3 = 0;
  for (int j0 = start; j0 < end; j0 += 16) {
    int idx = j0 + (lane & 15);
    bool ok = idx < end;
    int   sI = ok ? colsrc[idx] : 0;
    float aI = ok ? alpha[idx]  : 0.0f;
    #pragma unroll
    for (int t = 0; t < 16; t += 2) {
      if (j0 + t >= end) break;          // wave-uniform
      int   ss = __shfl(sI, t + half);
      float aa = __shfl(aI, t + half);
      float4 p = *(const float4*)(xw + (size_t)ss * HID + hl * 4);
      a0 += aa * p.x; a1 += aa * p.y; a2 += aa * p.z; a3 += aa * p.w;
    }
  }
  a0 += __shfl_xor(a0, 32); a1 += __shfl_xor(a1, 32);
  a2 += __shfl_xor(a2, 32); a3 += __shfl_xor(a3, 32);
  int col = hl * 4;
  float4 b = *(const float4*)(biasF + col);
  a0 += b.x; a1 += b.y; a2 += b.z; a3 += b.w;
  if (relu) { a0 = fmaxf(a0, 0.f); a1 = fmaxf(a1, 0.f); a2 = fmaxf(a2, 0.f); a3 = fmaxf(a3, 0.f); }
  if (half == 0) {
    size_t o = (size_t)node * HID + col;
    u16 h0 = f2b(a0), h1 = f2b(a1), h2 = f2b(a2), h3 = f2b(a3);
    ushort4 hv; hv.x = h0; hv.y = h1; hv.z = h2; hv.w = h3;
    *(ushort4*)(outH + o) = hv;
    ushort4 lv;
    lv.x = f2b(a0 - b2f(h0)); lv.y = f2b(a1 - b2f(h1));
    lv.z = f2b(a2 - b2f(h2)); lv.w = f2b(a3 - b2f(h3));
    *(ushort4*)(outL + o) = lv;
    if (out2) { out2[o] = a0; out2[o + 1] = a1; out2[o + 2] = a2; out2[o + 3] = a3; }
  }
  if (waSn) {   // next-layer attention dots from the in-register activation
    float4 ws = *(const float4*)(waSn + col);
    float4 wd = *(const float4*)(waDn + col);
    float vs = a0 * ws.x + a1 * ws.y + a2 * ws.z + a3 * ws.w;
    float vd = a0 * wd.x + a1 * wd.y + a2 * wd.z + a3 * wd.w;
    #pragma unroll
    for (int d = 1; d < 32; d <<= 1) { vs += __shfl_xor(vs, d); vd += __shfl_xor(vd, d); }
    if (lane == 0) { ssrc[node] = vs; sdst[node] = vd; }
  }
}

// ---------------- mean(hL) partial reduce (reads hi/lo planes, exact) ----------------

__global__ __launch_bounds__(256) void k_hbar(const u16* __restrict__ hH, const u16* __restrict__ hLo,
                                              float* __restrict__ hbar) {
  int t = threadIdx.x;
  int col = t & 127, g = t >> 7;
  float acc = 0.0f;
  for (int n = blockIdx.x * 2 + g; n < N_NODES; n += gridDim.x * 2) {
    size_t o = (size_t)n * HID + col;
    acc += b2f(hH[o]) + b2f(hLo[o]);
  }
  atomicAdd(&hbar[col], acc);
}

// ---------------- y = sigmoid(d2 @ Wh^T + bh) ----------------

__global__ __launch_bounds__(256) void k_ydot(const float* __restrict__ d2,
    const float* __restrict__ Whf, const float* __restrict__ bhf, float* __restrict__ yout)
{
  int node = blockIdx.x * 4 + (threadIdx.x >> 6);
  int lane = threadIdx.x & 63;
  float2 p = *(const float2*)(d2 + (size_t)node * HID + lane * 2);
  float v = p.x * Whf[lane * 2] + p.y * Whf[lane * 2 + 1];
  #pragma unroll
  for (int d = 1; d < 64; d <<= 1) v += __shfl_xor(v, d);
  if (lane == 0) {
    float s = 1.0f / (1.0f + __expf(-(v + bhf[0])));
    yout[node] = s;
  }
}

// ---------------- t = sigmoid(mean(hL) @ Wt^T + bt) ----------------

__global__ void k_tker(const float* __restrict__ hbar, const float* __restrict__ Wtf,
                       const float* __restrict__ btf, float* __restrict__ tout) {
  int lane = threadIdx.x;  // 64 threads
  float v = hbar[lane] * Wtf[lane] + hbar[lane + 64] * Wtf[lane + 64];
  #pragma unroll
  for (int d = 1; d < 64; d <<= 1) v += __shfl_xor(v, d);
  if (lane == 0) {
    float t = 1.0f / (1.0f + __expf(-(v * (1.0f / N_NODES) + btf[0])));
    tout[0] = t;
  }
}

// ---------------- launch ----------------

extern "C" void kernel_launch(void* const* d_in, const int* in_sizes, int n_in,
                              void* d_out, int out_size, void* d_ws, size_t ws_size,
                              hipStream_t stream) {
  const void* x    = d_in[0];
  const void* h    = d_in[1];
  const int*  ei   = (const int*)d_in[2];
  const void* Wenc = d_in[3];
  const void* benc = d_in[4];
  const void* Wg   = d_in[5];
  const void* atts = d_in[6];
  const void* attd = d_in[7];
  const void* bg   = d_in[8];
  const void* Wd   = d_in[9];
  const void* bd   = d_in[10];
  const void* Wd1  = d_in[11];
  const void* bd1v = d_in[12];
  const void* Wh   = d_in[13];
  const void* bh   = d_in[14];
  const void* Wt   = d_in[15];
  const void* bt   = d_in[16];
  float* outF = (float*)d_out;   // reference output dtype is float32

  char* w = (char*)d_ws;
  auto alloc = [&](size_t bytes) { char* p = w; w += (bytes + 255) & ~(size_t)255; return p; };
  const size_t NPLANE = (size_t)N_NODES * HID;       // 6.4M elems
  float* xwF    = (float*)alloc(NPLANE * 4);         // conv GEMM out (messages, f32)
  u16*   zH     = (u16*)  alloc(NPLANE * 2);
  u16*   zL     = (u16*)  alloc(NPLANE * 2);
  u16*   aH     = (u16*)  alloc(NPLANE * 2);         // contiguous with aL (d2F aliases both)
  u16*   aL     = (u16*)  alloc(NPLANE * 2);
  float* ssrc   = (float*)alloc((size_t)N_NODES * 4);
  float* sdst   = (float*)alloc((size_t)N_NODES * 4);
  int*   deg    = (int*)  alloc((size_t)N_NODES * 4);
  int*   rowp   = (int*)  alloc((size_t)(N_NODES + 1) * 4);
  int*   cursor = (int*)  alloc((size_t)N_NODES * 4);
  int*   colsrc = (int*)  alloc((size_t)E_TOT * 4);
  float* alpha  = (float*)alloc((size_t)E_TOT * 4);
  int*   blkSum = (int*)  alloc(1024);
  int*   blkOff = (int*)  alloc(1024);
  float* hbar   = (float*)alloc(512);
  int*   flags  = (int*)  alloc(256);
  u16*   WencH  = (u16*)  alloc(24576 * 2);
  u16*   WencL  = (u16*)  alloc(24576 * 2);
  u16*   WgH    = (u16*)  alloc(49152 * 2);
  u16*   WgL    = (u16*)  alloc(49152 * 2);
  u16*   WdH    = (u16*)  alloc(32768 * 2);
  u16*   WdL    = (u16*)  alloc(32768 * 2);
  u16*   Wd1H   = (u16*)  alloc(16384 * 2);
  u16*   Wd1L   = (u16*)  alloc(16384 * 2);
  float* vecf   = (float*)alloc(2048 * 4);
  float* waS    = (float*)alloc(3 * HID * 4);
  float* waD    = (float*)alloc(3 * HID * 4);
  // aliases (strictly after last reader in stream order):
  u16*   dH     = (u16*)xwF;            // decoder1 out planes reuse xwF
  u16*   dL     = dH + NPLANE;
  float* d2F    = (float*)aH;           // decoder2 out reuses a-planes

  const int NODE_BLKS = N_NODES / 4;                   // 12500
  const int EDGE_BLKS = (E_TOT + 255) / 256;           // 3321
  const int SCAN_BLKS = (N_NODES + 255) / 256;         // 196
  const int GEMM_BLKS = ((N_NODES + 31) / 32 + 3) / 4; // 391
  const int CONV_BLKS = (124674 + 255) / 256;          // 488

  // dtype detection, then param conversion + att-dot precompute
  k_detect<<<1, 64, 0, stream>>>(x, ei, flags);
  k_convert<<<CONV_BLKS, 256, 0, stream>>>(Wenc, Wg, Wd, Wd1, benc, bg, atts, attd,
                                           bd, bd1v, Wh, bh, Wt, bt,
                                           WencH, WencL, WgH, WgL, WdH, WdL,
                                           Wd1H, Wd1L, vecf, flags);
  k_wa<<<3, 256, 0, stream>>>(WgH, WgL, vecf, waS, waD);

  // CSR build
  hipMemsetAsync(deg, 0, (size_t)N_NODES * 4, stream);
  hipMemsetAsync(hbar, 0, 128 * sizeof(float), stream);
  k_deg<<<EDGE_BLKS, 256, 0, stream>>>(ei, deg, flags);
  k_scan_block<<<SCAN_BLKS, 256, 0, stream>>>(deg, rowp, blkSum, N_NODES, nullptr);
  k_scan_block<<<1, 256, 0, stream>>>(blkSum, blkOff, nullptr, SCAN_BLKS, rowp + N_NODES);
  k_scan_add<<<SCAN_BLKS, 256, 0, stream>>>(rowp, blkOff, cursor, N_NODES);
  k_scatter<<<EDGE_BLKS, 256, 0, stream>>>(ei, cursor, colsrc, flags);

  // Encoder: z = concat(x,h) @ Wenc^T + benc -> z planes; then layer-0 att dots
  k_gemm<<<GEMM_BLKS, 256, 0, stream>>>(x, nullptr, 64, 64, h, nullptr, HID,
                                        WencH, WencL, vecf,
                                        nullptr, zH, zL,
                                        N_NODES, 192, 0, 1, flags);
  k_sdots<<<NODE_BLKS, 256, 0, stream>>>(zH, zL, waS, waD, ssrc, sdst);

  // 4 GAT conv applications (layers 0,1,2 with relu; layer-2 params again, no relu)
  for (int l4 = 0; l4 < 4; ++l4) {
    int l = (l4 < 3) ? l4 : 2;
    int relu = (l4 < 3) ? 1 : 0;
    int lnext = (l4 + 1 < 3) ? (l4 + 1) : 2;           // weights used by conv l4+1
    const u16* inH = (l4 == 0) ? zH : aH;
    const u16* inL = (l4 == 0) ? zL : aL;
    k_gemm<<<GEMM_BLKS, 256, 0, stream>>>(inH, inL, HID, HID, nullptr, nullptr, HID,
                                          WgH + (size_t)l * HID * HID, WgL + (size_t)l * HID * HID,
                                          nullptr,
                                          xwF, nullptr, nullptr,
                                          N_NODES, HID, 0, 2, flags);
    k_softmax<<<NODE_BLKS, 256, 0, stream>>>(rowp, colsrc, ssrc, sdst, alpha);
    k_gather<<<NODE_BLKS, 256, 0, stream>>>(rowp, colsrc, alpha, xwF, vecf + 128 + l * HID,
                                            aH, aL, (l4 == 3) ? (outF + N_NODES + 1) : nullptr,
                                            (l4 < 3) ? (waS + lnext * HID) : nullptr,
                                            (l4 < 3) ? (waD + lnext * HID) : nullptr,
                                            ssrc, sdst, relu);
  }

  // termination head input: mean over nodes of hL (a planes)
  k_hbar<<<256, 256, 0, stream>>>(aH, aL, hbar);

  // Decoder (dH/dL alias xwF — free after last gather; d2F aliases a-planes — free after decoder1+hbar)
  k_gemm<<<GEMM_BLKS, 256, 0, stream>>>(aH, aL, HID, HID, zH, zL, HID,
                                        WdH, WdL, vecf + 1280,
                                        nullptr, dH, dL,
                                        N_NODES, 256, 1, 2, flags);
  k_gemm<<<GEMM_BLKS, 256, 0, stream>>>(dH, dL, HID, HID, nullptr, nullptr, HID,
                                        Wd1H, Wd1L, vecf + 1408,
                                        d2F, nullptr, nullptr,
                                        N_NODES, 128, 1, 2, flags);
  k_ydot<<<NODE_BLKS, 256, 0, stream>>>(d2F, vecf + 1536, vecf + 1664, outF);
  k_tker<<<1, 64, 0, stream>>>(hbar, vecf + 1665, vecf + 1793, outF + N_NODES);
}

// Round 8
// 719.918 us; speedup vs baseline: 1.1734x; 1.1734x over previous
//
#include <hip/hip_runtime.h>

#define N_NODES 50000
#define N_EDGES 800000
#define E_TOT   (N_EDGES + N_NODES)   // with self loops
#define HID     128

typedef unsigned short u16;
typedef unsigned int   u32;
typedef __bf16 bf16x8 __attribute__((ext_vector_type(8)));
typedef float  f32x4  __attribute__((ext_vector_type(4)));

__device__ __forceinline__ float b2f(u16 u) {
  union { u32 i; float f; } c; c.i = ((u32)u) << 16; return c.f;
}
__device__ __forceinline__ u16 f2b(float f) {
  union { float f; u32 i; } c; c.f = f;
  u32 u = c.i;
  return (u16)((u + 0x7fffu + ((u >> 16) & 1u)) >> 16);  // RNE
}

// ---------------- runtime dtype detection ----------------

__global__ void k_detect(const void* x, const void* ei, int* flags) {
  int lane = threadIdx.x;              // 64 threads
  const u16* xw = (const u16*)x;
  int wildF = 0;
  #pragma unroll
  for (int i = 0; i < 4; ++i) {
    u16 w = xw[lane + 64 * i];
    int e = (w >> 7) & 0xff;
    if (e >= 0x89) wildF = 1;          // |bf16| >= 1024: impossible for N(0,1) bf16
  }
  unsigned long long bF = __ballot(wildF);
  const int* e32 = (const int*)ei;
  int nzOdd = 0;
  #pragma unroll
  for (int i = 0; i < 2; ++i)
    if (e32[2 * (lane + 64 * i) + 1] != 0) nzOdd = 1;
  unsigned long long bI = __ballot(nzOdd);
  if (lane == 0) {
    flags[0] = (bF != 0ull) ? 1 : 0;
    flags[1] = (bI != 0ull) ? 0 : 1;   // odd words all zero -> int64
  }
}

// ---------------- param conversion: weights -> bf16 hi/lo planes, vectors -> f32 ----------------

__global__ __launch_bounds__(256) void k_convert(
    const void* Wenc, const void* Wg, const void* Wd, const void* Wd1,
    const void* benc, const void* bg, const void* atts, const void* attd,
    const void* bd, const void* bd1, const void* Wh, const void* bh,
    const void* Wt, const void* bt,
    u16* WencH, u16* WencL, u16* WgH, u16* WgL, u16* WdH, u16* WdL,
    u16* Wd1H, u16* Wd1L, float* vecf, const int* flags)
{
  int isF32 = flags[0];
  int t = blockIdx.x * 256 + threadIdx.x;
  auto ld = [&](const void* p, int i) -> float {
    return isF32 ? ((const float*)p)[i] : b2f(((const u16*)p)[i]);
  };
  auto sp = [&](u16* H, u16* L, int i, float v) {
    u16 hh = f2b(v); H[i] = hh; L[i] = f2b(v - b2f(hh));
  };
  if      (t < 24576)  { sp(WencH, WencL, t, ld(Wenc, t)); }
  else if (t < 73728)  { int i = t - 24576;  sp(WgH,  WgL,  i, ld(Wg, i)); }
  else if (t < 106496) { int i = t - 73728;  sp(WdH,  WdL,  i, ld(Wd, i)); }
  else if (t < 122880) { int i = t - 106496; sp(Wd1H, Wd1L, i, ld(Wd1, i)); }
  else if (t < 123008) { int i = t - 122880; vecf[i]        = ld(benc, i); }
  else if (t < 123392) { int i = t - 123008; vecf[128 + i]  = ld(bg, i); }
  else if (t < 123776) { int i = t - 123392; vecf[512 + i]  = ld(atts, i); }
  else if (t < 124160) { int i = t - 123776; vecf[896 + i]  = ld(attd, i); }
  else if (t < 124288) { int i = t - 124160; vecf[1280 + i] = ld(bd, i); }
  else if (t < 124416) { int i = t - 124288; vecf[1408 + i] = ld(bd1, i); }
  else if (t < 124544) { int i = t - 124416; vecf[1536 + i] = ld(Wh, i); }
  else if (t == 124544) { vecf[1664] = ld(bh, 0); }
  else if (t < 124673) { int i = t - 124545; vecf[1665 + i] = ld(Wt, i); }
  else if (t == 124673) { vecf[1793] = ld(bt, 0); }
}

// ---------------- CSR build ----------------

__device__ __forceinline__ int ld_ei(const int* ei, size_t idx, int i64) {
  int v = i64 ? (int)((const long long*)ei)[idx] : ei[idx];
  return ((unsigned)v < (unsigned)N_NODES) ? v : 0;  // defensive clamp
}

__global__ void k_deg(const int* __restrict__ ei, int* __restrict__ deg, const int* flags) {
  int i64 = flags[1];
  int k = blockIdx.x * 256 + threadIdx.x;
  if (k >= E_TOT) return;
  int d = (k < N_EDGES) ? ld_ei(ei, (size_t)N_EDGES + k, i64) : (k - N_EDGES);
  atomicAdd(&deg[d], 1);
}

__device__ __forceinline__ int block_scan_excl(int v, int lane, int w, int* wsum, int& total) {
  int x = v;
  #pragma unroll
  for (int d = 1; d < 64; d <<= 1) {
    int y = __shfl_up(x, d);
    if (lane >= d) x += y;
  }
  if (lane == 63) wsum[w] = x;
  __syncthreads();
  int wOff = 0;
  #pragma unroll
  for (int i = 0; i < 4; ++i) wOff += (i < w) ? wsum[i] : 0;
  total = wsum[0] + wsum[1] + wsum[2] + wsum[3];
  return wOff + x - v;  // exclusive
}

__global__ void k_scan_block(const int* __restrict__ in, int* __restrict__ outExcl,
                             int* __restrict__ blkSum, int n, int* __restrict__ totalOut) {
  __shared__ int wsum[4];
  int t = threadIdx.x, lane = t & 63, w = t >> 6;
  int gid = blockIdx.x * 256 + t;
  int v = (gid < n) ? in[gid] : 0;
  int total;
  int excl = block_scan_excl(v, lane, w, wsum, total);
  if (gid < n) outExcl[gid] = excl;
  if (t == 0) {
    if (blkSum)   blkSum[blockIdx.x] = total;
    if (totalOut) totalOut[0] = total;
  }
}

__global__ void k_scan_add(int* __restrict__ rowp, const int* __restrict__ blkOff,
                           int* __restrict__ cursor, int n) {
  int gid = blockIdx.x * 256 + threadIdx.x;
  if (gid < n) {
    int r = rowp[gid] + blkOff[blockIdx.x];
    rowp[gid] = r;
    cursor[gid] = r;
  }
}

__global__ void k_scatter(const int* __restrict__ ei, int* __restrict__ cursor,
                          int* __restrict__ colsrc, const int* flags) {
  int i64 = flags[1];
  int k = blockIdx.x * 256 + threadIdx.x;
  if (k >= E_TOT) return;
  int s, d;
  if (k < N_EDGES) { s = ld_ei(ei, k, i64); d = ld_ei(ei, (size_t)N_EDGES + k, i64); }
  else             { s = d = k - N_EDGES; }
  int pos = atomicAdd(&cursor[d], 1);
  colsrc[pos] = s;
}

// ---------------- MFMA GEMM, split-bf16 3-term + optional fused attention dots ----------------
// out[N,128] = concat(A1,A2)[N,K] @ W[128,K]^T (+bias)(+relu).
// aMode 1: A raw inputs (f32 split on the fly / bf16). aMode 2: A bf16 hi/lo planes.
// A layout: A[m=lane&15][k=quad*8+j]; B[k][n=lane&15]; D col=lane&15 row=quad*4+reg.

__device__ __forceinline__ void loadSplit8(const float* p, bf16x8& hi, bf16x8& lo) {
  union { u16 a[8]; bf16x8 v; } H, L;
  #pragma unroll
  for (int i = 0; i < 8; ++i) {
    float v = p[i];
    u16 hh = f2b(v);
    H.a[i] = hh;
    L.a[i] = f2b(v - b2f(hh));
  }
  hi = H.v; lo = L.v;
}

__global__ __launch_bounds__(256) void k_gemm(
    const void* A1a, const void* A1b, int s1, int K1,
    const void* A2a, const void* A2b, int s2,
    const u16* __restrict__ WH, const u16* __restrict__ WL,
    const float* __restrict__ biasF,
    float* __restrict__ outF_, u16* __restrict__ outH, u16* __restrict__ outL,
    const float* __restrict__ asv, const float* __restrict__ adv,
    float* __restrict__ ssrc, float* __restrict__ sdst,
    int N, int K, int relu, int aMode, const int* flags)
{
  int isF32 = flags[0];
  int wid  = blockIdx.x * 4 + (threadIdx.x >> 6);
  int lane = threadIdx.x & 63;
  int q = lane >> 4, c = lane & 15;
  int nb = wid * 32;
  if (nb >= N) return;
  f32x4 acc[2][8] = {};
  int r0 = nb + c;      if (r0 > N - 1) r0 = N - 1;
  int r1 = nb + 16 + c; if (r1 > N - 1) r1 = N - 1;

  for (int kb = 0; kb < K; kb += 32) {
    int kf = kb + q * 8;                   // lane's 8 contiguous k
    bf16x8 a0h, a1h, a0l, a1l;
    if (aMode == 1) {
      const void* Ap; int stride, ks;
      if (kf < K1) { Ap = A1a; stride = s1; ks = kf; }
      else         { Ap = A2a; stride = s2; ks = kf - K1; }
      if (isF32) {
        loadSplit8((const float*)Ap + (size_t)r0 * stride + ks, a0h, a0l);
        loadSplit8((const float*)Ap + (size_t)r1 * stride + ks, a1h, a1l);
      } else {
        union { u16 u[8]; bf16x8 v; } Z = {};
        a0h = *(const bf16x8*)((const u16*)Ap + (size_t)r0 * stride + ks);
        a1h = *(const bf16x8*)((const u16*)Ap + (size_t)r1 * stride + ks);
        a0l = Z.v; a1l = Z.v;
      }
    } else {
      const u16 *PH, *PL; int stride, ks;
      if (kf < K1) { PH = (const u16*)A1a; PL = (const u16*)A1b; stride = s1; ks = kf; }
      else         { PH = (const u16*)A2a; PL = (const u16*)A2b; stride = s2; ks = kf - K1; }
      a0h = *(const bf16x8*)(PH + (size_t)r0 * stride + ks);
      a0l = *(const bf16x8*)(PL + (size_t)r0 * stride + ks);
      a1h = *(const bf16x8*)(PH + (size_t)r1 * stride + ks);
      a1l = *(const bf16x8*)(PL + (size_t)r1 * stride + ks);
    }
    const u16* wph = WH + (size_t)c * K + kb + q * 8;
    const u16* wpl = WL + (size_t)c * K + kb + q * 8;
    #pragma unroll
    for (int ct = 0; ct < 8; ++ct) {
      bf16x8 bh_ = *(const bf16x8*)(wph + (size_t)(ct * 16) * K);
      bf16x8 bl_ = *(const bf16x8*)(wpl + (size_t)(ct * 16) * K);
      acc[0][ct] = __builtin_amdgcn_mfma_f32_16x16x32_bf16(a0h, bh_, acc[0][ct], 0, 0, 0);
      acc[1][ct] = __builtin_amdgcn_mfma_f32_16x16x32_bf16(a1h, bh_, acc[1][ct], 0, 0, 0);
      acc[0][ct] = __builtin_amdgcn_mfma_f32_16x16x32_bf16(a0h, bl_, acc[0][ct], 0, 0, 0);
      acc[1][ct] = __builtin_amdgcn_mfma_f32_16x16x32_bf16(a1h, bl_, acc[1][ct], 0, 0, 0);
      acc[0][ct] = __builtin_amdgcn_mfma_f32_16x16x32_bf16(a0l, bh_, acc[0][ct], 0, 0, 0);
      acc[1][ct] = __builtin_amdgcn_mfma_f32_16x16x32_bf16(a1l, bh_, acc[1][ct], 0, 0, 0);
    }
  }

  // epilogue: bias/relu + stores
  #pragma unroll
  for (int ct = 0; ct < 8; ++ct) {
    int col = ct * 16 + c;
    float bv = biasF ? biasF[col] : 0.0f;
    #pragma unroll
    for (int g = 0; g < 2; ++g) {
      #pragma unroll
      for (int r = 0; r < 4; ++r) {
        float vv = acc[g][ct][r] + bv;
        if (relu) vv = fmaxf(vv, 0.0f);
        acc[g][ct][r] = vv;
        int node = nb + g * 16 + q * 4 + r;
        if (node < N) {
          size_t o = (size_t)node * HID + col;
          if (outF_) outF_[o] = vv;
          if (outH) {
            u16 hh = f2b(vv);
            outH[o] = hh;
            outL[o] = f2b(vv - b2f(hh));
          }
        }
      }
    }
  }

  // fused attention score dots: ssrc/sdst[row] = xw[row,:]·a_s / ·a_d
  if (asv) {
    #pragma unroll
    for (int g = 0; g < 2; ++g) {
      #pragma unroll
      for (int r = 0; r < 4; ++r) {
        float ssum = 0.0f, dsum = 0.0f;
        #pragma unroll
        for (int ct = 0; ct < 8; ++ct) {
          int col = ct * 16 + c;
          float v = acc[g][ct][r];
          ssum += v * asv[col];
          dsum += v * adv[col];
        }
        #pragma unroll
        for (int m = 1; m < 16; m <<= 1) {
          ssum += __shfl_xor(ssum, m);
          dsum += __shfl_xor(dsum, m);
        }
        int node = nb + g * 16 + q * 4 + r;
        if (c == 0 && node < N) { ssrc[node] = ssum; sdst[node] = dsum; }
      }
    }
  }
}

// ---------------- fused softmax + weighted gather (wave per node) ----------------
// pass A/B: node-local softmax stats from ssrc gathers (first 64 edges cached in regs);
// pass C: alpha-on-the-fly weighted row gather (r6 8-edge MLP batching).

__global__ __launch_bounds__(256) void k_fused(const int* __restrict__ rowp,
    const int* __restrict__ colsrc, const float* __restrict__ ssrc,
    const float* __restrict__ sdst, const float* __restrict__ xw,
    const float* __restrict__ biasF,
    u16* __restrict__ outH, u16* __restrict__ outL,
    float* __restrict__ out2, int relu)
{
  int node = blockIdx.x * 4 + (threadIdx.x >> 6);
  int lane = threadIdx.x & 63;
  int half = lane >> 5, hl = lane & 31;
  int start = rowp[node], end = rowp[node + 1];
  float sdv = sdst[node];

  // pass A: leaky-relu scores; cache first 64 edges in registers
  int jC = start + lane;
  bool okC = jC < end;
  int   sC = okC ? colsrc[jC] : 0;
  float eC = -1e30f;
  if (okC) {
    float e = ssrc[sC] + sdv;
    eC = (e >= 0.0f) ? e : 0.2f * e;
  }
  float mx = eC;
  for (int j = start + 64 + lane; j < end; j += 64) {
    float e = ssrc[colsrc[j]] + sdv;
    e = (e >= 0.0f) ? e : 0.2f * e;
    mx = fmaxf(mx, e);
  }
  #pragma unroll
  for (int d = 1; d < 64; d <<= 1) mx = fmaxf(mx, __shfl_xor(mx, d));

  // pass B: sum of exp
  float sum = okC ? __expf(eC - mx) : 0.0f;
  for (int j = start + 64 + lane; j < end; j += 64) {
    float e = ssrc[colsrc[j]] + sdv;
    e = (e >= 0.0f) ? e : 0.2f * e;
    sum += __expf(e - mx);
  }
  #pragma unroll
  for (int d = 1; d < 64; d <<= 1) sum += __shfl_xor(sum, d);
  float inv = 1.0f / sum;                // self loop -> sum > 0
  float alC = okC ? __expf(eC - mx) * inv : 0.0f;  // this lane's cached-edge alpha

  // pass C: weighted row gather, 8-edge batches, dual-issue halves
  float a0 = 0, a1 = 0, a2 = 0, a3 = 0;
  for (int j0 = start; j0 < end; j0 += 8) {
    int base = j0 - start;               // wave-uniform
    int   sI; float aI;
    if (base < 64) {                     // cached batch: holders are lanes base..base+7
      sI = sC; aI = alC;
    } else {                             // tail (deg > 64): reload + recompute
      int idx = j0 + (lane & 7);
      bool ok = idx < end;
      sI = ok ? colsrc[idx] : 0;
      float e = ok ? (ssrc[sI] + sdv) : 0.0f;
      e = (e >= 0.0f) ? e : 0.2f * e;
      aI = ok ? __expf(e - mx) * inv : 0.0f;
    }
    int src = (base < 64) ? base : 0;    // shuffle source offset
    #pragma unroll
    for (int t = 0; t < 8; t += 2) {
      int   ss = __shfl(sI, src + t + half);
      float aa = __shfl(aI, src + t + half);
      float4 p = *(const float4*)(xw + (size_t)ss * HID + hl * 4);
      a0 += aa * p.x; a1 += aa * p.y; a2 += aa * p.z; a3 += aa * p.w;
    }
  }
  a0 += __shfl_xor(a0, 32); a1 += __shfl_xor(a1, 32);
  a2 += __shfl_xor(a2, 32); a3 += __shfl_xor(a3, 32);
  if (half == 0) {
    int col = hl * 4;
    float4 b = *(const float4*)(biasF + col);
    a0 += b.x; a1 += b.y; a2 += b.z; a3 += b.w;
    if (relu) { a0 = fmaxf(a0, 0.f); a1 = fmaxf(a1, 0.f); a2 = fmaxf(a2, 0.f); a3 = fmaxf(a3, 0.f); }
    size_t o = (size_t)node * HID + col;
    u16 h0 = f2b(a0), h1 = f2b(a1), h2 = f2b(a2), h3 = f2b(a3);
    ushort4 hv; hv.x = h0; hv.y = h1; hv.z = h2; hv.w = h3;
    *(ushort4*)(outH + o) = hv;
    ushort4 lv;
    lv.x = f2b(a0 - b2f(h0)); lv.y = f2b(a1 - b2f(h1));
    lv.z = f2b(a2 - b2f(h2)); lv.w = f2b(a3 - b2f(h3));
    *(ushort4*)(outL + o) = lv;
    if (out2) { out2[o] = a0; out2[o + 1] = a1; out2[o + 2] = a2; out2[o + 3] = a3; }
  }
}

// ---------------- mean(hL) partial reduce (reads hi/lo planes, exact) ----------------

__global__ __launch_bounds__(256) void k_hbar(const u16* __restrict__ hH, const u16* __restrict__ hLo,
                                              float* __restrict__ hbar) {
  int t = threadIdx.x;
  int col = t & 127, g = t >> 7;
  float acc = 0.0f;
  for (int n = blockIdx.x * 2 + g; n < N_NODES; n += gridDim.x * 2) {
    size_t o = (size_t)n * HID + col;
    acc += b2f(hH[o]) + b2f(hLo[o]);
  }
  atomicAdd(&hbar[col], acc);
}

// ---------------- y = sigmoid(d2 @ Wh^T + bh) ----------------

__global__ __launch_bounds__(256) void k_ydot(const float* __restrict__ d2,
    const float* __restrict__ Whf, const float* __restrict__ bhf, float* __restrict__ yout)
{
  int node = blockIdx.x * 4 + (threadIdx.x >> 6);
  int lane = threadIdx.x & 63;
  float2 p = *(const float2*)(d2 + (size_t)node * HID + lane * 2);
  float v = p.x * Whf[lane * 2] + p.y * Whf[lane * 2 + 1];
  #pragma unroll
  for (int d = 1; d < 64; d <<= 1) v += __shfl_xor(v, d);
  if (lane == 0) {
    float s = 1.0f / (1.0f + __expf(-(v + bhf[0])));
    yout[node] = s;
  }
}

// ---------------- t = sigmoid(mean(hL) @ Wt^T + bt) ----------------

__global__ void k_tker(const float* __restrict__ hbar, const float* __restrict__ Wtf,
                       const float* __restrict__ btf, float* __restrict__ tout) {
  int lane = threadIdx.x;  // 64 threads
  float v = hbar[lane] * Wtf[lane] + hbar[lane + 64] * Wtf[lane + 64];
  #pragma unroll
  for (int d = 1; d < 64; d <<= 1) v += __shfl_xor(v, d);
  if (lane == 0) {
    float t = 1.0f / (1.0f + __expf(-(v * (1.0f / N_NODES) + btf[0])));
    tout[0] = t;
  }
}

// ---------------- launch ----------------

extern "C" void kernel_launch(void* const* d_in, const int* in_sizes, int n_in,
                              void* d_out, int out_size, void* d_ws, size_t ws_size,
                              hipStream_t stream) {
  const void* x    = d_in[0];
  const void* h    = d_in[1];
  const int*  ei   = (const int*)d_in[2];
  const void* Wenc = d_in[3];
  const void* benc = d_in[4];
  const void* Wg   = d_in[5];
  const void* atts = d_in[6];
  const void* attd = d_in[7];
  const void* bg   = d_in[8];
  const void* Wd   = d_in[9];
  const void* bd   = d_in[10];
  const void* Wd1  = d_in[11];
  const void* bd1v = d_in[12];
  const void* Wh   = d_in[13];
  const void* bh   = d_in[14];
  const void* Wt   = d_in[15];
  const void* bt   = d_in[16];
  float* outF = (float*)d_out;   // reference output dtype is float32

  char* w = (char*)d_ws;
  auto alloc = [&](size_t bytes) { char* p = w; w += (bytes + 255) & ~(size_t)255; return p; };
  const size_t NPLANE = (size_t)N_NODES * HID;       // 6.4M elems
  float* xwF    = (float*)alloc(NPLANE * 4);         // conv GEMM out (messages, f32)
  u16*   zH     = (u16*)  alloc(NPLANE * 2);
  u16*   zL     = (u16*)  alloc(NPLANE * 2);
  u16*   aH     = (u16*)  alloc(NPLANE * 2);         // contiguous with aL (d2F aliases both)
  u16*   aL     = (u16*)  alloc(NPLANE * 2);
  float* ssrc   = (float*)alloc((size_t)N_NODES * 4);
  float* sdst   = (float*)alloc((size_t)N_NODES * 4);
  int*   deg    = (int*)  alloc((size_t)N_NODES * 4);
  int*   rowp   = (int*)  alloc((size_t)(N_NODES + 1) * 4);
  int*   cursor = (int*)  alloc((size_t)N_NODES * 4);
  int*   colsrc = (int*)  alloc((size_t)E_TOT * 4);
  int*   blkSum = (int*)  alloc(1024);
  int*   blkOff = (int*)  alloc(1024);
  float* hbar   = (float*)alloc(512);
  int*   flags  = (int*)  alloc(256);
  u16*   WencH  = (u16*)  alloc(24576 * 2);
  u16*   WencL  = (u16*)  alloc(24576 * 2);
  u16*   WgH    = (u16*)  alloc(49152 * 2);
  u16*   WgL    = (u16*)  alloc(49152 * 2);
  u16*   WdH    = (u16*)  alloc(32768 * 2);
  u16*   WdL    = (u16*)  alloc(32768 * 2);
  u16*   Wd1H   = (u16*)  alloc(16384 * 2);
  u16*   Wd1L   = (u16*)  alloc(16384 * 2);
  float* vecf   = (float*)alloc(2048 * 4);
  // aliases (strictly after last reader in stream order):
  u16*   dH     = (u16*)xwF;            // decoder1 out planes reuse xwF
  u16*   dL     = dH + NPLANE;
  float* d2F    = (float*)aH;           // decoder2 out reuses a-planes

  const int NODE_BLKS = N_NODES / 4;                   // 12500
  const int EDGE_BLKS = (E_TOT + 255) / 256;           // 3321
  const int SCAN_BLKS = (N_NODES + 255) / 256;         // 196
  const int GEMM_BLKS = ((N_NODES + 31) / 32 + 3) / 4; // 391
  const int CONV_BLKS = (124674 + 255) / 256;          // 488

  // dtype detection, then param conversion
  k_detect<<<1, 64, 0, stream>>>(x, ei, flags);
  k_convert<<<CONV_BLKS, 256, 0, stream>>>(Wenc, Wg, Wd, Wd1, benc, bg, atts, attd,
                                           bd, bd1v, Wh, bh, Wt, bt,
                                           WencH, WencL, WgH, WgL, WdH, WdL,
                                           Wd1H, Wd1L, vecf, flags);

  // CSR build
  hipMemsetAsync(deg, 0, (size_t)N_NODES * 4, stream);
  hipMemsetAsync(hbar, 0, 128 * sizeof(float), stream);
  k_deg<<<EDGE_BLKS, 256, 0, stream>>>(ei, deg, flags);
  k_scan_block<<<SCAN_BLKS, 256, 0, stream>>>(deg, rowp, blkSum, N_NODES, nullptr);
  k_scan_block<<<1, 256, 0, stream>>>(blkSum, blkOff, nullptr, SCAN_BLKS, rowp + N_NODES);
  k_scan_add<<<SCAN_BLKS, 256, 0, stream>>>(rowp, blkOff, cursor, N_NODES);
  k_scatter<<<EDGE_BLKS, 256, 0, stream>>>(ei, cursor, colsrc, flags);

  // Encoder: z = concat(x,h) @ Wenc^T + benc -> z planes
  k_gemm<<<GEMM_BLKS, 256, 0, stream>>>(x, nullptr, 64, 64, h, nullptr, HID,
                                        WencH, WencL, vecf,
                                        nullptr, zH, zL,
                                        nullptr, nullptr, nullptr, nullptr,
                                        N_NODES, 192, 0, 1, flags);

  // 4 GAT conv applications (layers 0,1,2 with relu; layer-2 params again, no relu)
  for (int l4 = 0; l4 < 4; ++l4) {
    int l = (l4 < 3) ? l4 : 2;
    int relu = (l4 < 3) ? 1 : 0;
    const u16* inH = (l4 == 0) ? zH : aH;
    const u16* inL = (l4 == 0) ? zL : aL;
    k_gemm<<<GEMM_BLKS, 256, 0, stream>>>(inH, inL, HID, HID, nullptr, nullptr, HID,
                                          WgH + (size_t)l * HID * HID, WgL + (size_t)l * HID * HID,
                                          nullptr,
                                          xwF, nullptr, nullptr,
                                          vecf + 512 + l * HID, vecf + 896 + l * HID, ssrc, sdst,
                                          N_NODES, HID, 0, 2, flags);
    k_fused<<<NODE_BLKS, 256, 0, stream>>>(rowp, colsrc, ssrc, sdst, xwF, vecf + 128 + l * HID,
                                           aH, aL, (l4 == 3) ? (outF + N_NODES + 1) : nullptr, relu);
  }

  // termination head input: mean over nodes of hL (a planes)
  k_hbar<<<256, 256, 0, stream>>>(aH, aL, hbar);

  // Decoder (dH/dL alias xwF — free after last fused gather; d2F aliases a-planes — free after decoder1+hbar)
  k_gemm<<<GEMM_BLKS, 256, 0, stream>>>(aH, aL, HID, HID, zH, zL, HID,
                                        WdH, WdL, vecf + 1280,
                                        nullptr, dH, dL,
                                        nullptr, nullptr, nullptr, nullptr,
                                        N_NODES, 256, 1, 2, flags);
  k_gemm<<<GEMM_BLKS, 256, 0, stream>>>(dH, dL, HID, HID, nullptr, nullptr, HID,
                                        Wd1H, Wd1L, vecf + 1408,
                                        d2F, nullptr, nullptr,
                                        nullptr, nullptr, nullptr, nullptr,
                                        N_NODES, 128, 1, 2, flags);
  k_ydot<<<NODE_BLKS, 256, 0, stream>>>(d2F, vecf + 1536, vecf + 1664, outF);
  k_tker<<<1, 64, 0, stream>>>(hbar, vecf + 1665, vecf + 1793, outF + N_NODES);
}